// Round 1
// baseline (226.839 us; speedup 1.0000x reference)
//
#include <hip/hip_runtime.h>

#define TPB 256
#define NFFT 1024

// XOR swizzle: bijective within each 32-slot window; breaks power-of-2 stride
// bank patterns. Reads (stride-256) and pass-0/3 writes become <=2-way (free);
// pass-1/2 writes ~4-way (1.58x on those instrs only).
__device__ __forceinline__ int sw(int i) { return i ^ ((i >> 5) & 31); }

__device__ __forceinline__ float2 cmul(float2 a, float2 b) {
  return make_float2(a.x * b.x - a.y * b.y, a.x * b.y + a.y * b.x);
}
__device__ __forceinline__ float2 cadd(float2 a, float2 b) { return make_float2(a.x + b.x, a.y + b.y); }
__device__ __forceinline__ float2 csub(float2 a, float2 b) { return make_float2(a.x - b.x, a.y - b.y); }

// y_k = sum_r v_r * e^{-2*pi*i*k*r/4}
__device__ __forceinline__ void dft4(const float2 v[4], float2 y[4]) {
  float2 s02 = cadd(v[0], v[2]), d02 = csub(v[0], v[2]);
  float2 s13 = cadd(v[1], v[3]), d13 = csub(v[1], v[3]);
  y[0] = cadd(s02, s13);
  y[2] = csub(s02, s13);
  y[1] = make_float2(d02.x + d13.y, d02.y - d13.x);  // d02 + (-i)*d13
  y[3] = make_float2(d02.x - d13.y, d02.y + d13.x);  // d02 + (+i)*d13
}

// Stockham radix-4 autosort FFT, N=1024, natural order in/out, forward
// (twiddle e^{-i...}). One block per batch row; 256 threads x 4 complex each.
__global__ __launch_bounds__(TPB) void fft1024_kernel(const float* __restrict__ in,
                                                      float* __restrict__ out) {
  __shared__ float2 bufA[NFFT];
  __shared__ float2 bufB[NFFT];
  const int j = threadIdx.x;
  const float2* xin = reinterpret_cast<const float2*>(in) + (size_t)blockIdx.x * NFFT;
  float2* xout = reinterpret_cast<float2*>(out) + (size_t)blockIdx.x * NFFT;

  float2 v[4], y[4];

  // ---- pass 0: Ns = 1 (no twiddle). global -> LDS(A)
  #pragma unroll
  for (int r = 0; r < 4; ++r) v[r] = xin[j + 256 * r];
  dft4(v, y);
  #pragma unroll
  for (int r = 0; r < 4; ++r) bufA[sw(4 * j + r)] = y[r];
  __syncthreads();

  // ---- passes 1..3: LDS ping-pong. Ns = 4, 16, 64
  float2* cur = bufA;
  float2* nxt = bufB;
  #pragma unroll
  for (int p = 1; p <= 3; ++p) {
    const int Ns = 1 << (2 * p);
    #pragma unroll
    for (int r = 0; r < 4; ++r) v[r] = cur[sw(j + 256 * r)];

    const float ang = -6.283185307179586f * (float)(j & (Ns - 1)) / (float)(4 * Ns);
    float sn, cs;
    __sincosf(ang, &sn, &cs);
    float2 w1 = make_float2(cs, sn);
    float2 w2 = cmul(w1, w1);
    float2 w3 = cmul(w2, w1);
    v[1] = cmul(v[1], w1);
    v[2] = cmul(v[2], w2);
    v[3] = cmul(v[3], w3);

    dft4(v, y);
    const int idxD = ((j & ~(Ns - 1)) << 2) | (j & (Ns - 1));  // (j/Ns)*4Ns + j%Ns
    #pragma unroll
    for (int r = 0; r < 4; ++r) nxt[sw(idxD + r * Ns)] = y[r];
    __syncthreads();
    float2* tmp = cur; cur = nxt; nxt = tmp;
  }

  // ---- pass 4: Ns = 256. LDS -> global (idxD == j, coalesced writes)
  #pragma unroll
  for (int r = 0; r < 4; ++r) v[r] = cur[sw(j + 256 * r)];
  {
    const int Ns = 256;
    const float ang = -6.283185307179586f * (float)(j & (Ns - 1)) / (float)(4 * Ns);
    float sn, cs;
    __sincosf(ang, &sn, &cs);
    float2 w1 = make_float2(cs, sn);
    float2 w2 = cmul(w1, w1);
    float2 w3 = cmul(w2, w1);
    v[1] = cmul(v[1], w1);
    v[2] = cmul(v[2], w2);
    v[3] = cmul(v[3], w3);
    dft4(v, y);
    #pragma unroll
    for (int r = 0; r < 4; ++r) xout[j + 256 * r] = y[r];
  }
}

extern "C" void kernel_launch(void* const* d_in, const int* in_sizes, int n_in,
                              void* d_out, int out_size, void* d_ws, size_t ws_size,
                              hipStream_t stream) {
  const float* x = (const float*)d_in[0];
  float* out = (float*)d_out;
  const int rows = in_sizes[0] / (2 * NFFT);  // 16384 rows of 1024 complex
  fft1024_kernel<<<rows, TPB, 0, stream>>>(x, out);
}